// Round 5
// baseline (232.166 us; speedup 1.0000x reference)
//
#include <hip/hip_runtime.h>
#include <hip/hip_fp16.h>
#include <math.h>

#define LRELU_ALPHA 0.2f
#define NEG_INF -1000000000.0f

constexpr int B_ = 8, N_ = 2048, FIN = 128, FOUT = 64;

typedef _Float16 __attribute__((ext_vector_type(8))) f16x8;
typedef float __attribute__((ext_vector_type(4))) f32x4;

// async global->LDS: lds dest = wave-uniform base, HW appends lane*16
__device__ __forceinline__ void gload16(const void* g, void* l) {
  __builtin_amdgcn_global_load_lds(
      (const __attribute__((address_space(1))) void*)g,
      (__attribute__((address_space(3))) void*)l, 16, 0, 0);
}

// ---------------------------------------------------------------------------
// Kernel 1: Wh = h @ W^T (fp32), emitted fp16 transposed WhT[b][o][n];
// s1 = Wh@a1, s2 = Wh@a2 (fp32). ~4 us, not the bottleneck.
// ---------------------------------------------------------------------------
__global__ __launch_bounds__(256) void k_wh(
    const float* __restrict__ h, const float* __restrict__ W,
    const float* __restrict__ a, unsigned short* __restrict__ WhT,
    float* __restrict__ s1, float* __restrict__ s2) {
  __shared__ float Wt[128][65];  // [f][o]: read bank (f+o)%32 -> conflict-free
  __shared__ float hs[16][128];

  const int t = threadIdx.x;
  const int row0 = blockIdx.x * 16;

  for (int e = t; e < 64 * 128; e += 256) {
    int o = e >> 7, f = e & 127;
    Wt[f][o] = W[e];
  }
  {
    const float4* hg = (const float4*)(h + (size_t)row0 * FIN);
    for (int i4 = t; i4 < 16 * 32; i4 += 256) {
      int r = i4 >> 5, f4 = i4 & 31;
      *(float4*)&hs[r][f4 * 4] = hg[i4];
    }
  }
  __syncthreads();

  const int wave = t >> 6, lane = t & 63;  // lane = o
  float acc[4] = {0.f, 0.f, 0.f, 0.f};
#pragma unroll 4
  for (int f4 = 0; f4 < 32; ++f4) {
    float w0 = Wt[4 * f4 + 0][lane], w1 = Wt[4 * f4 + 1][lane];
    float w2 = Wt[4 * f4 + 2][lane], w3 = Wt[4 * f4 + 3][lane];
#pragma unroll
    for (int r = 0; r < 4; ++r) {
      float4 hv = *(const float4*)&hs[wave * 4 + r][f4 * 4];
      acc[r] += hv.x * w0 + hv.y * w1 + hv.z * w2 + hv.w * w3;
    }
  }

  const float a1v = a[lane], a2v = a[64 + lane];
  const int b = row0 / N_;
#pragma unroll
  for (int r = 0; r < 4; ++r) {
    const int row = row0 + wave * 4 + r;
    const int n = row - b * N_;
    const float v = acc[r];
    WhT[((size_t)b * 64 + lane) * N_ + n] = __half_as_ushort(__float2half(v));
    float p1 = v * a1v, p2 = v * a2v;
#pragma unroll
    for (int d = 32; d; d >>= 1) {
      p1 += __shfl_xor(p1, d, 64);
      p2 += __shfl_xor(p2, d, 64);
    }
    if (lane == 0) { s1[row] = p1; s2[row] = p2; }
  }
}

// ---------------------------------------------------------------------------
// Kernel 2: masked softmax + att@Wh. R5: 16 i-rows/block, grid 1024 ->
// 4 resident blocks/CU (cross-block overlap hides barrier drains).
// Chunk = 64 j, 12 KB staged (adj 16x64 int + WhT 64x64 fp16) by 12
// global_load_lds_dwordx4 (3/wave), double-buffered sA/sB.
// Wave w = (oh = w&1: o-half, jh = w>>1: j-half). Per chunk per wave:
// 2 int4 adj + 2 b128 B-frag LDS reads, 8 exp/lane, 2 MFMA 16x16x32 f16.
// p = exp(lrelu(s1+s2) - 2) keeps p in fp16 range (ratios exact).
// Epilogue merges the jh pairs via LDS (reuses sA).
// ---------------------------------------------------------------------------
__global__ __launch_bounds__(256, 4) void k_attn(
    const unsigned short* __restrict__ WhT,
    const float* __restrict__ s1g, const float* __restrict__ s2g,
    const int* __restrict__ adj, float* __restrict__ out) {
  __shared__ __align__(16) unsigned char sA[12 * 1024];
  __shared__ __align__(16) unsigned char sB[12 * 1024];
  __shared__ float s2s[N_];  // 8 KB

  const int t = threadIdx.x;
  const int wave = t >> 6, lane = t & 63;
  const int m = lane & 15, q = lane >> 4;
  const int b = blockIdx.y;
  const int i0 = blockIdx.x * 16;
  const int oh = wave & 1;   // o-half: o-groups {2oh, 2oh+1}
  const int jh = wave >> 1;  // j-half of each 64-chunk

  const int* adjB = adj + (size_t)b * N_ * N_;
  const unsigned short* whB = WhT + (size_t)b * 64 * N_;

  // preload full s2 row (8 KB, L2-hot)
  {
    const float4* s2R = (const float4*)(s2g + b * N_);
    ((float4*)s2s)[t] = s2R[t];
    ((float4*)s2s)[256 + t] = s2R[256 + t];
  }

  const float s1r = s1g[b * N_ + i0 + m];

  // staging: 12 instrs/chunk, flat ii = wave*3 + k
  //  ii 0..3  : adj slot (ks=ii>>1, hh=ii&1), lane (m,q) loads
  //             adj[i0+m][ks*32+q*8+hh*4 ..+4], chunk stride 256 B
  //  ii 4..11 : WhT slot (g=(ii-4)>>1, ks=(ii-4)&1), lane (m,q) loads
  //             WhT[g*16+m][ks*32+q*8 ..+8], chunk stride 128 B
  const unsigned char* gp[3];
  int gstr[3], loff[3];
#pragma unroll
  for (int k = 0; k < 3; ++k) {
    const int ii = wave * 3 + k;
    if (ii < 4) {
      int ks = ii >> 1, hh = ii & 1;
      gp[k] = (const unsigned char*)(adjB + (size_t)(i0 + m) * N_ + ks * 32 +
                                     q * 8 + hh * 4);
      gstr[k] = 64 * 4;
    } else {
      int g = (ii - 4) >> 1, ks = (ii - 4) & 1;
      gp[k] = (const unsigned char*)(whB + (size_t)(g * 16 + m) * N_ +
                                     ks * 32 + q * 8);
      gstr[k] = 64 * 2;
    }
    loff[k] = ii * 1024;
  }

#define STAGE(S, c)                                                      \
  {                                                                      \
    _Pragma("unroll") for (int k = 0; k < 3; ++k)                        \
        gload16(gp[k] + (size_t)(c) * gstr[k], (S) + loff[k]);           \
  }

  f32x4 acc0 = {0.f, 0.f, 0.f, 0.f}, acc1 = acc0;
  float lsum = 0.f;

  auto consume = [&](const unsigned char* base, int c) {
    int4 A0 = *(const int4*)(base + (jh * 2 + 0) * 1024 + lane * 16);
    int4 A1 = *(const int4*)(base + (jh * 2 + 1) * 1024 + lane * 16);
    const float* sp = &s2s[c * 64 + jh * 32 + q * 8];
    float4 sv0 = *(const float4*)sp;
    float4 sv1 = *(const float4*)(sp + 4);
    // interleave: A0/A1 each hold 4 ints for j-offsets hh*4..hh*4+4 within
    // the lane's 8-j strip: strip j = jh*32+q*8+jj, jj<8: jj<4 -> A0, else A1
    float xs[8] = {sv0.x, sv0.y, sv0.z, sv0.w, sv1.x, sv1.y, sv1.z, sv1.w};
    int avs[8] = {A0.x, A0.y, A0.z, A0.w, A1.x, A1.y, A1.z, A1.w};
    f16x8 af;
#pragma unroll
    for (int j = 0; j < 8; ++j) {
      float x = s1r + xs[j];
      float e = fmaxf(x, LRELU_ALPHA * x);
      e = avs[j] ? (e - 2.0f) : NEG_INF;  // -2: fp16 range headroom
      float p = __expf(e);                // masked -> exactly 0.0f
      lsum += p;
      af[j] = (_Float16)p;
    }
    f16x8 b0 = *(const f16x8*)(base + (4 + (2 * oh) * 2 + jh) * 1024 + lane * 16);
    f16x8 b1 = *(const f16x8*)(base + (4 + (2 * oh + 1) * 2 + jh) * 1024 + lane * 16);
    acc0 = __builtin_amdgcn_mfma_f32_16x16x32_f16(af, b0, acc0, 0, 0, 0);
    acc1 = __builtin_amdgcn_mfma_f32_16x16x32_f16(af, b1, acc1, 0, 0, 0);
  };

  STAGE(sA, 0);
  __syncthreads();  // chunk 0 staged + s2s visible

  for (int cc = 0; cc < 16; ++cc) {
    const int c0 = 2 * cc, c1 = 2 * cc + 1;
    STAGE(sB, c1);       // in flight during consume(sA)
    consume(sA, c0);
    __syncthreads();
    if (c1 + 1 < 32) STAGE(sA, c1 + 1);
    consume(sB, c1);
    __syncthreads();
  }

  // ---- epilogue: merge jh pairs (reuse sA) ----
  float* accm = (float*)sA;         // [4][64][8] = 8 KB
  float* lsml = (float*)(sA + 8192);  // [4][16]

  lsum += __shfl_xor(lsum, 16, 64);
  lsum += __shfl_xor(lsum, 32, 64);  // row-m sum over this wave's j-half
  // (no barrier needed before overwrite: last loop iter ended with barrier)
  if (lane < 16) lsml[wave * 16 + lane] = lsum;
#pragma unroll
  for (int r = 0; r < 4; ++r) {
    accm[(wave * 64 + lane) * 8 + r] = acc0[r];
    accm[(wave * 64 + lane) * 8 + 4 + r] = acc1[r];
  }
  __syncthreads();

  // out element (ri, o): og = o>>4, oh' = og>>1, a = og&1; src waves
  // w = oh' (jh=0) and 2+oh' (jh=1); src lane = (ri>>2)*16 + (o&15),
  // slot = a*4 + (ri&3). lsum full = lsml[0][ri] + lsml[2][ri].
#pragma unroll
  for (int kk = 0; kk < 4; ++kk) {
    int e = kk * 256 + t;
    int ri = e >> 6, o = e & 63;
    int og = o >> 4, ohp = og >> 1, a = og & 1;
    int sl = (ri >> 2) * 16 + (o & 15);
    int slot = a * 4 + (ri & 3);
    float v = accm[(ohp * 64 + sl) * 8 + slot] +
              accm[((2 + ohp) * 64 + sl) * 8 + slot];
    float l = lsml[ri] + lsml[2 * 16 + ri];
    if (l == 0.f) l = 1.f;  // fully-masked row guard
    out[((size_t)b * N_ + i0 + ri) * FOUT + o] = v / l;
  }
#undef STAGE
}

extern "C" void kernel_launch(void* const* d_in, const int* in_sizes, int n_in,
                              void* d_out, int out_size, void* d_ws, size_t ws_size,
                              hipStream_t stream) {
  const float* h   = (const float*)d_in[0];
  const int*   adj = (const int*)d_in[1];
  const float* W   = (const float*)d_in[2];
  const float* a   = (const float*)d_in[3];
  float* out = (float*)d_out;

  // ws: WhT fp16 (2 MB) | s1 (64 KB) | s2 (64 KB)
  unsigned short* WhT = (unsigned short*)d_ws;
  float* s1 = (float*)(WhT + (size_t)B_ * 64 * N_);
  float* s2 = s1 + (size_t)B_ * N_;

  k_wh<<<dim3(B_ * N_ / 16), 256, 0, stream>>>(h, W, a, WhT, s1, s2);
  k_attn<<<dim3(N_ / 16, B_), 256, 0, stream>>>(WhT, s1, s2, adj, out);
}